// Round 1
// baseline (636.616 us; speedup 1.0000x reference)
//
#include <hip/hip_runtime.h>
#include <cstdint>
#include <cstddef>

#define BB 32
#define SS 4096
#define DD 512
#define AA 3
#define KK 4
#define OUTD 512

#define NCHUNK 32
#define ROWS_PER_BLOCK (SS / NCHUNK)        // 128
#define ROWS_PER_WAVE  (ROWS_PER_BLOCK / 4) // 32

// Small-weights LDS layout:
// [0..11]  centers (K*A = 12)
// [12..14] ba (3)
// [15..32] Wh (3*6 = 18)   Wh[a][i] at 15 + a*6 + i
// [33..38] bh (6)
// [39..62] Wk (6*4 = 24)   Wk[i][k] at 39 + i*4 + k
// [63..66] bk (4)

__global__ __launch_bounds__(256, 4) void fused_pool_kernel(
    const float* __restrict__ x, const float* __restrict__ centers,
    const float* __restrict__ Wa, const float* __restrict__ ba,
    const float* __restrict__ Wh, const float* __restrict__ bh,
    const float* __restrict__ Wk, const float* __restrict__ bk,
    float* __restrict__ pooled)
{
    __shared__ float sw[68];
    __shared__ float red[4 * 2048];   // 32 KB: per-wave pooled partials

    const int tid  = threadIdx.x;
    const int wave = tid >> 6;
    const int lane = tid & 63;
    const int b     = blockIdx.y;
    const int chunk = blockIdx.x;

    if (tid < 12)      sw[tid] = centers[tid];
    else if (tid < 15) sw[tid] = ba[tid - 12];
    else if (tid < 33) sw[tid] = Wh[tid - 15];
    else if (tid < 39) sw[tid] = bh[tid - 33];
    else if (tid < 63) sw[tid] = Wk[tid - 39];
    else if (tid < 67) sw[tid] = bk[tid - 63];
    __syncthreads();

    const int d0 = lane * 8;

    // Per-lane Wa slice: Wa[(d0+j)*3 + a] for j=0..7 -> 24 contiguous floats
    float wa[24];
    {
        const float* wp = Wa + (size_t)d0 * 3;
        #pragma unroll
        for (int j = 0; j < 24; ++j) wa[j] = wp[j];
    }

    float acc[KK][8];
    #pragma unroll
    for (int k = 0; k < KK; ++k)
        #pragma unroll
        for (int j = 0; j < 8; ++j) acc[k][j] = 0.0f;

    const int s_base = chunk * ROWS_PER_BLOCK + wave * ROWS_PER_WAVE;
    const float* xb = x + (size_t)b * SS * DD + d0;

    // prefetch row 0
    const float* xr0 = xb + (size_t)s_base * DD;
    float4 nx0 = ((const float4*)xr0)[0];
    float4 nx1 = ((const float4*)xr0)[1];

    #pragma unroll 1
    for (int i = 0; i < ROWS_PER_WAVE; ++i) {
        float4 x0 = nx0, x1 = nx1;
        if (i + 1 < ROWS_PER_WAVE) {
            const float* xn = xb + (size_t)(s_base + i + 1) * DD;
            nx0 = ((const float4*)xn)[0];
            nx1 = ((const float4*)xn)[1];
        }
        float xa[8] = {x0.x, x0.y, x0.z, x0.w, x1.x, x1.y, x1.z, x1.w};

        // partial af over this lane's 8 d's
        float p0 = 0.f, p1 = 0.f, p2 = 0.f;
        #pragma unroll
        for (int j = 0; j < 8; ++j) {
            p0 += xa[j] * wa[j * 3 + 0];
            p1 += xa[j] * wa[j * 3 + 1];
            p2 += xa[j] * wa[j * 3 + 2];
        }
        // 64-lane butterfly reduce (all lanes end with the full sum)
        #pragma unroll
        for (int off = 32; off >= 1; off >>= 1) {
            p0 += __shfl_xor(p0, off, 64);
            p1 += __shfl_xor(p1, off, 64);
            p2 += __shfl_xor(p2, off, 64);
        }
        const float af0 = p0 + sw[12];
        const float af1 = p1 + sw[13];
        const float af2 = p2 + sw[14];

        // L2 distances to K centers
        float dist[KK];
        #pragma unroll
        for (int k = 0; k < KK; ++k) {
            float da = af0 - sw[k * 3 + 0];
            float db = af1 - sw[k * 3 + 1];
            float dc = af2 - sw[k * 3 + 2];
            dist[k] = sqrtf(da * da + db * db + dc * dc);
        }
        // dw = softmax(-dist): max(-dist) = -min(dist)
        float mn = fminf(fminf(dist[0], dist[1]), fminf(dist[2], dist[3]));
        float e[KK]; float esum = 0.f;
        #pragma unroll
        for (int k = 0; k < KK; ++k) { e[k] = __expf(mn - dist[k]); esum += e[k]; }
        const float einv = 1.0f / esum;

        // tiny MLP: h = relu(af @ Wh + bh); base = h @ Wk + bk
        float h[6];
        #pragma unroll
        for (int i6 = 0; i6 < 6; ++i6) {
            float v = af0 * sw[15 + i6] + af1 * sw[21 + i6] + af2 * sw[27 + i6] + sw[33 + i6];
            h[i6] = fmaxf(v, 0.0f);
        }
        float logit[KK];
        #pragma unroll
        for (int k = 0; k < KK; ++k) {
            float v = sw[63 + k];
            #pragma unroll
            for (int i6 = 0; i6 < 6; ++i6) v += h[i6] * sw[39 + i6 * 4 + k];
            logit[k] = v + e[k] * einv;   // base + distance_weights
        }
        // fw = softmax(logit)
        float mx = fmaxf(fmaxf(logit[0], logit[1]), fmaxf(logit[2], logit[3]));
        float f[KK]; float fsum = 0.f;
        #pragma unroll
        for (int k = 0; k < KK; ++k) { f[k] = __expf(logit[k] - mx); fsum += f[k]; }
        const float finv = 1.0f / fsum;

        #pragma unroll
        for (int k = 0; k < KK; ++k) {
            const float fw = f[k] * finv;
            #pragma unroll
            for (int j = 0; j < 8; ++j) acc[k][j] += fw * xa[j];
        }
    }

    // cross-wave reduction in LDS, then one global atomic per cell per block
    #pragma unroll
    for (int k = 0; k < KK; ++k)
        #pragma unroll
        for (int j = 0; j < 8; ++j)
            red[wave * 2048 + k * 512 + d0 + j] = acc[k][j];
    __syncthreads();

    float* pb = pooled + (size_t)b * (KK * DD);
    for (int c = tid; c < 2048; c += 256) {
        float s = red[c] + red[2048 + c] + red[4096 + c] + red[6144 + c];
        unsafeAtomicAdd(&pb[c], s);
    }
}

// out[b][col] = bout[col] + sum_j pooled[b][j] * Wout[j][col]
// grid: (colchunk 2, b 32, jchunk 4), block 256
__global__ __launch_bounds__(256) void out_gemm_kernel(
    const float* __restrict__ pooled, const float* __restrict__ Wout,
    const float* __restrict__ bout, float* __restrict__ out)
{
    __shared__ float p_sh[512];
    const int tid = threadIdx.x;
    const int cc = blockIdx.x, b = blockIdx.y, jc = blockIdx.z;

    p_sh[tid]       = pooled[b * 2048 + jc * 512 + tid];
    p_sh[tid + 256] = pooled[b * 2048 + jc * 512 + tid + 256];
    __syncthreads();

    const int col = cc * 256 + tid;
    const float* wp = Wout + (size_t)(jc * 512) * OUTD + col;
    float acc = 0.f;
    #pragma unroll 8
    for (int jj = 0; jj < 512; ++jj) {
        acc += p_sh[jj] * wp[(size_t)jj * OUTD];
    }
    if (jc == 0) acc += bout[col];
    unsafeAtomicAdd(&out[b * OUTD + col], acc);
}

extern "C" void kernel_launch(void* const* d_in, const int* in_sizes, int n_in,
                              void* d_out, int out_size, void* d_ws, size_t ws_size,
                              hipStream_t stream) {
    (void)in_sizes; (void)n_in; (void)out_size; (void)ws_size;
    const float* x       = (const float*)d_in[0];
    const float* centers = (const float*)d_in[1];
    const float* Wa      = (const float*)d_in[2];
    const float* ba      = (const float*)d_in[3];
    const float* Wh      = (const float*)d_in[4];
    const float* bh      = (const float*)d_in[5];
    const float* Wk      = (const float*)d_in[6];
    const float* bk      = (const float*)d_in[7];
    const float* Wout    = (const float*)d_in[8];
    const float* bout    = (const float*)d_in[9];
    float* out    = (float*)d_out;
    float* pooled = (float*)d_ws;   // B*K*D floats = 256 KB

    hipMemsetAsync(pooled, 0, (size_t)BB * KK * DD * sizeof(float), stream);
    hipMemsetAsync(out, 0, (size_t)BB * OUTD * sizeof(float), stream);

    fused_pool_kernel<<<dim3(NCHUNK, BB), 256, 0, stream>>>(
        x, centers, Wa, ba, Wh, bh, Wk, bk, pooled);
    out_gemm_kernel<<<dim3(2, BB, 4), 256, 0, stream>>>(pooled, Wout, bout, out);
}

// Round 2
// 614.805 us; speedup vs baseline: 1.0355x; 1.0355x over previous
//
#include <hip/hip_runtime.h>
#include <cstdint>
#include <cstddef>

#define BB 32
#define SS 4096
#define DD 512
#define AA 3
#define KK 4
#define OUTD 512

#define NCHUNK 32
#define ROWS_PER_BLOCK (SS / NCHUNK)        // 128
#define ROWS_PER_WAVE  (ROWS_PER_BLOCK / 4) // 32

// Small-weights LDS layout:
// [0..11]  centers (K*A = 12)
// [12..14] ba (3)
// [15..32] Wh (3*6 = 18)   Wh[a][i] at 15 + a*6 + i
// [33..38] bh (6)
// [39..62] Wk (6*4 = 24)   Wk[i][k] at 39 + i*4 + k
// [63..66] bk (4)

// waves_per_eu(4,4): pin exactly 4 waves/EU (16 waves/CU, VGPR cap 128).
// R1 lesson: __launch_bounds__(256,4) alone let the backend chase 8 waves/EU
// -> 64 VGPRs -> wa[24] spilled to scratch -> 768 MiB of spill re-reads
// (FETCH_SIZE 956 MiB vs 256 MiB ideal).
__global__ __launch_bounds__(256)
__attribute__((amdgpu_waves_per_eu(4, 4)))
void fused_pool_kernel(
    const float* __restrict__ x, const float* __restrict__ centers,
    const float* __restrict__ Wa, const float* __restrict__ ba,
    const float* __restrict__ Wh, const float* __restrict__ bh,
    const float* __restrict__ Wk, const float* __restrict__ bk,
    float* __restrict__ pooled)
{
    __shared__ float sw[68];
    __shared__ float red[4 * 2048];   // 32 KB: per-wave pooled partials

    const int tid  = threadIdx.x;
    const int wave = tid >> 6;
    const int lane = tid & 63;
    const int b     = blockIdx.y;
    const int chunk = blockIdx.x;

    if (tid < 12)      sw[tid] = centers[tid];
    else if (tid < 15) sw[tid] = ba[tid - 12];
    else if (tid < 33) sw[tid] = Wh[tid - 15];
    else if (tid < 39) sw[tid] = bh[tid - 33];
    else if (tid < 63) sw[tid] = Wk[tid - 39];
    else if (tid < 67) sw[tid] = bk[tid - 63];
    __syncthreads();

    const int d0 = lane * 8;

    // Per-lane Wa slice: Wa[(d0+j)*3 + a] for j=0..7 -> 24 contiguous floats
    float wa[24];
    {
        const float* wp = Wa + (size_t)d0 * 3;
        #pragma unroll
        for (int j = 0; j < 24; ++j) wa[j] = wp[j];
    }

    float acc[KK][8];
    #pragma unroll
    for (int k = 0; k < KK; ++k)
        #pragma unroll
        for (int j = 0; j < 8; ++j) acc[k][j] = 0.0f;

    const int s_base = chunk * ROWS_PER_BLOCK + wave * ROWS_PER_WAVE;
    const float* xb = x + (size_t)b * SS * DD + d0;

    // prefetch row 0
    const float* xr0 = xb + (size_t)s_base * DD;
    float4 nx0 = ((const float4*)xr0)[0];
    float4 nx1 = ((const float4*)xr0)[1];

    #pragma unroll 1
    for (int i = 0; i < ROWS_PER_WAVE; ++i) {
        float4 x0 = nx0, x1 = nx1;
        if (i + 1 < ROWS_PER_WAVE) {
            const float* xn = xb + (size_t)(s_base + i + 1) * DD;
            nx0 = ((const float4*)xn)[0];
            nx1 = ((const float4*)xn)[1];
        }
        float xa[8] = {x0.x, x0.y, x0.z, x0.w, x1.x, x1.y, x1.z, x1.w};

        // partial af over this lane's 8 d's
        float p0 = 0.f, p1 = 0.f, p2 = 0.f;
        #pragma unroll
        for (int j = 0; j < 8; ++j) {
            p0 += xa[j] * wa[j * 3 + 0];
            p1 += xa[j] * wa[j * 3 + 1];
            p2 += xa[j] * wa[j * 3 + 2];
        }
        // 64-lane butterfly reduce (all lanes end with the full sum)
        #pragma unroll
        for (int off = 32; off >= 1; off >>= 1) {
            p0 += __shfl_xor(p0, off, 64);
            p1 += __shfl_xor(p1, off, 64);
            p2 += __shfl_xor(p2, off, 64);
        }
        const float af0 = p0 + sw[12];
        const float af1 = p1 + sw[13];
        const float af2 = p2 + sw[14];

        // L2 distances to K centers
        float dist[KK];
        #pragma unroll
        for (int k = 0; k < KK; ++k) {
            float da = af0 - sw[k * 3 + 0];
            float db = af1 - sw[k * 3 + 1];
            float dc = af2 - sw[k * 3 + 2];
            dist[k] = sqrtf(da * da + db * db + dc * dc);
        }
        // dw = softmax(-dist): max(-dist) = -min(dist)
        float mn = fminf(fminf(dist[0], dist[1]), fminf(dist[2], dist[3]));
        float e[KK]; float esum = 0.f;
        #pragma unroll
        for (int k = 0; k < KK; ++k) { e[k] = __expf(mn - dist[k]); esum += e[k]; }
        const float einv = 1.0f / esum;

        // tiny MLP: h = relu(af @ Wh + bh); base = h @ Wk + bk
        float h[6];
        #pragma unroll
        for (int i6 = 0; i6 < 6; ++i6) {
            float v = af0 * sw[15 + i6] + af1 * sw[21 + i6] + af2 * sw[27 + i6] + sw[33 + i6];
            h[i6] = fmaxf(v, 0.0f);
        }
        float logit[KK];
        #pragma unroll
        for (int k = 0; k < KK; ++k) {
            float v = sw[63 + k];
            #pragma unroll
            for (int i6 = 0; i6 < 6; ++i6) v += h[i6] * sw[39 + i6 * 4 + k];
            logit[k] = v + e[k] * einv;   // base + distance_weights
        }
        // fw = softmax(logit)
        float mx = fmaxf(fmaxf(logit[0], logit[1]), fmaxf(logit[2], logit[3]));
        float f[KK]; float fsum = 0.f;
        #pragma unroll
        for (int k = 0; k < KK; ++k) { f[k] = __expf(logit[k] - mx); fsum += f[k]; }
        const float finv = 1.0f / fsum;

        #pragma unroll
        for (int k = 0; k < KK; ++k) {
            const float fw = f[k] * finv;
            #pragma unroll
            for (int j = 0; j < 8; ++j) acc[k][j] += fw * xa[j];
        }
    }

    // cross-wave reduction in LDS, then one global atomic per cell per block
    #pragma unroll
    for (int k = 0; k < KK; ++k)
        #pragma unroll
        for (int j = 0; j < 8; ++j)
            red[wave * 2048 + k * 512 + d0 + j] = acc[k][j];
    __syncthreads();

    float* pb = pooled + (size_t)b * (KK * DD);
    for (int c = tid; c < 2048; c += 256) {
        float s = red[c] + red[2048 + c] + red[4096 + c] + red[6144 + c];
        unsafeAtomicAdd(&pb[c], s);
    }
}

// out[b][col] = bout[col] + sum_j pooled[b][j] * Wout[j][col]
// grid: (colchunk 2, b 32, jchunk 16), block 256
// R1 lesson: jc=4 gave only 256 blocks (1 block/CU) -> latency-starved on
// the 512 strided Wout loads. jc=16 -> 1024 blocks, 128 j's each.
__global__ __launch_bounds__(256) void out_gemm_kernel(
    const float* __restrict__ pooled, const float* __restrict__ Wout,
    const float* __restrict__ bout, float* __restrict__ out)
{
    __shared__ float p_sh[128];
    const int tid = threadIdx.x;
    const int cc = blockIdx.x, b = blockIdx.y, jc = blockIdx.z;

    if (tid < 128) p_sh[tid] = pooled[b * 2048 + jc * 128 + tid];
    __syncthreads();

    const int col = cc * 256 + tid;
    const float* wp = Wout + (size_t)(jc * 128) * OUTD + col;
    float acc = 0.f;
    #pragma unroll 8
    for (int jj = 0; jj < 128; ++jj) {
        acc += p_sh[jj] * wp[(size_t)jj * OUTD];
    }
    if (jc == 0) acc += bout[col];
    unsafeAtomicAdd(&out[b * OUTD + col], acc);
}

extern "C" void kernel_launch(void* const* d_in, const int* in_sizes, int n_in,
                              void* d_out, int out_size, void* d_ws, size_t ws_size,
                              hipStream_t stream) {
    (void)in_sizes; (void)n_in; (void)out_size; (void)ws_size;
    const float* x       = (const float*)d_in[0];
    const float* centers = (const float*)d_in[1];
    const float* Wa      = (const float*)d_in[2];
    const float* ba      = (const float*)d_in[3];
    const float* Wh      = (const float*)d_in[4];
    const float* bh      = (const float*)d_in[5];
    const float* Wk      = (const float*)d_in[6];
    const float* bk      = (const float*)d_in[7];
    const float* Wout    = (const float*)d_in[8];
    const float* bout    = (const float*)d_in[9];
    float* out    = (float*)d_out;
    float* pooled = (float*)d_ws;   // B*K*D floats = 256 KB

    hipMemsetAsync(pooled, 0, (size_t)BB * KK * DD * sizeof(float), stream);
    hipMemsetAsync(out, 0, (size_t)BB * OUTD * sizeof(float), stream);

    fused_pool_kernel<<<dim3(NCHUNK, BB), 256, 0, stream>>>(
        x, centers, Wa, ba, Wh, bh, Wk, bk, pooled);
    out_gemm_kernel<<<dim3(2, BB, 16), 256, 0, stream>>>(pooled, Wout, bout, out);
}

// Round 3
// 429.077 us; speedup vs baseline: 1.4837x; 1.4329x over previous
//
#include <hip/hip_runtime.h>
#include <cstdint>
#include <cstddef>

#define BB 32
#define SS 4096
#define DD 512
#define AA 3
#define KK 4
#define OUTD 512

#define NCHUNK 32
#define ROWS_PER_BLOCK (SS / NCHUNK)        // 128
#define ROWS_PER_WAVE  (ROWS_PER_BLOCK / 4) // 32
#define TILE 8
#define NTILES (ROWS_PER_WAVE / TILE)       // 4

// Small-weights LDS layout (sw):
// [0..11]  centers (K*A = 12)
// [12..14] ba (3)
// [15..32] Wh (3*6 = 18)   Wh[a][i] at 15 + a*6 + i
// [33..38] bh (6)
// [39..62] Wk (6*4 = 24)   Wk[i][k] at 39 + i*4 + k
// [63..66] bk (4)
//
// R2 lesson: the single fused loop needed wa[24]+acc[32]+xa[8] live at once
// (~80 regs); allocator pinned 64 VGPRs and spilled wa -> 768 MiB of scratch
// re-reads (FETCH 956 MiB vs 256 ideal). waves_per_eu attributes did NOT
// move the allocator. Fix is structural: per-tile phase split so wa (phase 1)
// and acc (phase 2) are never simultaneously live; wa reloaded from LDS per
// tile; acc flushed to LDS red[] per tile; fw handed between phases via LDS.
// Phase 2 re-reads its 8-row tile (16 KB) moments after phase 1 fetched it,
// so the second read hits L1/L2/LLC, not HBM.
__global__ __launch_bounds__(256) void fused_pool_kernel(
    const float* __restrict__ x, const float* __restrict__ centers,
    const float* __restrict__ Wa, const float* __restrict__ ba,
    const float* __restrict__ Wh, const float* __restrict__ bh,
    const float* __restrict__ Wk, const float* __restrict__ bk,
    float* __restrict__ pooled)
{
    __shared__ float  sw[68];
    __shared__ float  wa_lds[DD * AA];        // 6 KB: Wa staged for per-tile reload
    __shared__ float4 fw_lds[4 * TILE];       // [wave][rowInTile] -> fw[4]
    __shared__ float  red[4 * 2048];          // 32 KB: per-wave pooled partials

    const int tid  = threadIdx.x;
    const int wave = tid >> 6;
    const int lane = tid & 63;
    const int b     = blockIdx.y;
    const int chunk = blockIdx.x;

    if (tid < 12)      sw[tid] = centers[tid];
    else if (tid < 15) sw[tid] = ba[tid - 12];
    else if (tid < 33) sw[tid] = Wh[tid - 15];
    else if (tid < 39) sw[tid] = bh[tid - 33];
    else if (tid < 63) sw[tid] = Wk[tid - 39];
    else if (tid < 67) sw[tid] = bk[tid - 63];
    #pragma unroll
    for (int i = 0; i < 6; ++i)
        wa_lds[tid * 6 + i] = Wa[tid * 6 + i];        // 256*6 = 1536 floats
    for (int i = tid; i < 4 * 2048; i += 256)
        red[i] = 0.0f;
    __syncthreads();

    const int d0 = lane * 8;
    const int s_base = chunk * ROWS_PER_BLOCK + wave * ROWS_PER_WAVE;
    const float* xb = x + (size_t)b * SS * DD + d0;

    #pragma unroll 1
    for (int t = 0; t < NTILES; ++t) {
        const int s0 = s_base + t * TILE;

        // ---- Phase 1: weights for TILE rows (wa live, acc NOT live) ----
        {
            float wa[24];
            const float4* wsrc = (const float4*)(wa_lds + d0 * 3);  // 96 B/lane
            #pragma unroll
            for (int i = 0; i < 6; ++i)
                ((float4*)wa)[i] = wsrc[i];

            #pragma unroll 1
            for (int r = 0; r < TILE; ++r) {
                const float* xr = xb + (size_t)(s0 + r) * DD;
                float4 x0 = ((const float4*)xr)[0];
                float4 x1 = ((const float4*)xr)[1];
                float xa[8] = {x0.x, x0.y, x0.z, x0.w, x1.x, x1.y, x1.z, x1.w};

                float p0 = 0.f, p1 = 0.f, p2 = 0.f;
                #pragma unroll
                for (int j = 0; j < 8; ++j) {
                    p0 += xa[j] * wa[j * 3 + 0];
                    p1 += xa[j] * wa[j * 3 + 1];
                    p2 += xa[j] * wa[j * 3 + 2];
                }
                #pragma unroll
                for (int off = 32; off >= 1; off >>= 1) {
                    p0 += __shfl_xor(p0, off, 64);
                    p1 += __shfl_xor(p1, off, 64);
                    p2 += __shfl_xor(p2, off, 64);
                }
                const float af0 = p0 + sw[12];
                const float af1 = p1 + sw[13];
                const float af2 = p2 + sw[14];

                float dist[KK];
                #pragma unroll
                for (int k = 0; k < KK; ++k) {
                    float da = af0 - sw[k * 3 + 0];
                    float db = af1 - sw[k * 3 + 1];
                    float dc = af2 - sw[k * 3 + 2];
                    dist[k] = sqrtf(da * da + db * db + dc * dc);
                }
                float mn = fminf(fminf(dist[0], dist[1]), fminf(dist[2], dist[3]));
                float e[KK]; float esum = 0.f;
                #pragma unroll
                for (int k = 0; k < KK; ++k) { e[k] = __expf(mn - dist[k]); esum += e[k]; }
                const float einv = 1.0f / esum;

                float h[6];
                #pragma unroll
                for (int i6 = 0; i6 < 6; ++i6) {
                    float v = af0 * sw[15 + i6] + af1 * sw[21 + i6]
                            + af2 * sw[27 + i6] + sw[33 + i6];
                    h[i6] = fmaxf(v, 0.0f);
                }
                float logit[KK];
                #pragma unroll
                for (int k = 0; k < KK; ++k) {
                    float v = sw[63 + k];
                    #pragma unroll
                    for (int i6 = 0; i6 < 6; ++i6) v += h[i6] * sw[39 + i6 * 4 + k];
                    logit[k] = v + e[k] * einv;
                }
                float mx = fmaxf(fmaxf(logit[0], logit[1]), fmaxf(logit[2], logit[3]));
                float f0 = __expf(logit[0] - mx), f1 = __expf(logit[1] - mx);
                float f2 = __expf(logit[2] - mx), f3 = __expf(logit[3] - mx);
                const float finv = 1.0f / (f0 + f1 + f2 + f3);

                if (lane == 0) {
                    float4 fwv = {f0 * finv, f1 * finv, f2 * finv, f3 * finv};
                    fw_lds[wave * TILE + r] = fwv;
                }
            }
        }

        // ---- Phase 2: pooling for the same TILE rows (acc live, wa NOT) ----
        {
            float acc[KK][8];
            #pragma unroll
            for (int k = 0; k < KK; ++k)
                #pragma unroll
                for (int j = 0; j < 8; ++j) acc[k][j] = 0.0f;

            #pragma unroll 2
            for (int r = 0; r < TILE; ++r) {
                const float* xr = xb + (size_t)(s0 + r) * DD;
                float4 x0 = ((const float4*)xr)[0];   // L1/L2-hot re-read
                float4 x1 = ((const float4*)xr)[1];
                float xa[8] = {x0.x, x0.y, x0.z, x0.w, x1.x, x1.y, x1.z, x1.w};
                float4 fwv = fw_lds[wave * TILE + r]; // broadcast read

                #pragma unroll
                for (int j = 0; j < 8; ++j) {
                    acc[0][j] += fwv.x * xa[j];
                    acc[1][j] += fwv.y * xa[j];
                    acc[2][j] += fwv.z * xa[j];
                    acc[3][j] += fwv.w * xa[j];
                }
            }

            float* rw = red + wave * 2048;
            #pragma unroll
            for (int k = 0; k < KK; ++k)
                #pragma unroll
                for (int j = 0; j < 8; ++j)
                    rw[k * 512 + d0 + j] += acc[k][j];
        }
    }

    __syncthreads();

    float* pb = pooled + (size_t)b * (KK * DD);
    for (int c = tid; c < 2048; c += 256) {
        float s = red[c] + red[2048 + c] + red[4096 + c] + red[6144 + c];
        unsafeAtomicAdd(&pb[c], s);
    }
}

// out[b][col] = bout[col] + sum_j pooled[b][j] * Wout[j][col]
// grid: (colchunk 2, b 32, jchunk 16), block 256  (kept from R2)
__global__ __launch_bounds__(256) void out_gemm_kernel(
    const float* __restrict__ pooled, const float* __restrict__ Wout,
    const float* __restrict__ bout, float* __restrict__ out)
{
    __shared__ float p_sh[128];
    const int tid = threadIdx.x;
    const int cc = blockIdx.x, b = blockIdx.y, jc = blockIdx.z;

    if (tid < 128) p_sh[tid] = pooled[b * 2048 + jc * 128 + tid];
    __syncthreads();

    const int col = cc * 256 + tid;
    const float* wp = Wout + (size_t)(jc * 128) * OUTD + col;
    float acc = 0.f;
    #pragma unroll 8
    for (int jj = 0; jj < 128; ++jj) {
        acc += p_sh[jj] * wp[(size_t)jj * OUTD];
    }
    if (jc == 0) acc += bout[col];
    unsafeAtomicAdd(&out[b * OUTD + col], acc);
}

extern "C" void kernel_launch(void* const* d_in, const int* in_sizes, int n_in,
                              void* d_out, int out_size, void* d_ws, size_t ws_size,
                              hipStream_t stream) {
    (void)in_sizes; (void)n_in; (void)out_size; (void)ws_size;
    const float* x       = (const float*)d_in[0];
    const float* centers = (const float*)d_in[1];
    const float* Wa      = (const float*)d_in[2];
    const float* ba      = (const float*)d_in[3];
    const float* Wh      = (const float*)d_in[4];
    const float* bh      = (const float*)d_in[5];
    const float* Wk      = (const float*)d_in[6];
    const float* bk      = (const float*)d_in[7];
    const float* Wout    = (const float*)d_in[8];
    const float* bout    = (const float*)d_in[9];
    float* out    = (float*)d_out;
    float* pooled = (float*)d_ws;   // B*K*D floats = 256 KB

    hipMemsetAsync(pooled, 0, (size_t)BB * KK * DD * sizeof(float), stream);
    hipMemsetAsync(out, 0, (size_t)BB * OUTD * sizeof(float), stream);

    fused_pool_kernel<<<dim3(NCHUNK, BB), 256, 0, stream>>>(
        x, centers, Wa, ba, Wh, bh, Wk, bk, pooled);
    out_gemm_kernel<<<dim3(2, BB, 16), 256, 0, stream>>>(pooled, Wout, bout, out);
}